// Round 1
// 1296.001 us; speedup vs baseline: 1.5815x; 1.5815x over previous
//
#include <hip/hip_runtime.h>
#include <math.h>

#define BSZ 16
#define NWW 17
#define NRR 116
#define WSS 10
#define EMB 128
#define LAYN 5
#define DST 16
#define SEQL 1160
#define FRQ 581
#define EDD 170
#define LAMW 0.01f
#define EPSW 1e-5f
#define NBW (BSZ*NWW)     // 272

// split-precision scales for f16 MFMA emulation of fp32 GEMM
#define SXF 1024.0f              // X scale (2^10)
#define SWF 4096.0f              // W scale (2^12)
#define INVS 2.384185791015625e-07f  // 1/(SXF*SWF) = 2^-22

typedef _Float16 half8 __attribute__((ext_vector_type(8)));
typedef float float4v __attribute__((ext_vector_type(4)));

__device__ __forceinline__ float softplus_f(float x){
    return fmaxf(x, 0.f) + log1pf(expf(-fabsf(x)));
}
__device__ __forceinline__ float sigmoid_f(float x){
    return 1.f / (1.f + expf(-x));
}

// ---- trig tables: tab[k] = cos/sin(2*pi*k/SEQL), double precision ----
__global__ void k_tables(float* tc, float* ts){
    int k = blockIdx.x*256 + threadIdx.x;
    if (k < SEQL){
        double th = (6.283185307179586476925286766559 * (double)k) / (double)SEQL;
        tc[k] = (float)cos(th);
        ts[k] = (float)sin(th);
    }
}
// DFT matrices, t-major (for forward) and f-major (for inverse)
__global__ void k_mk_tmaj(const float* tc, const float* ts, float* Ct, float* St){
    int id = blockIdx.x*256 + threadIdx.x;
    if (id >= SEQL*FRQ) return;
    int f = id % FRQ, t = id / FRQ;
    int idx = (f*t) % SEQL;
    Ct[id] = tc[idx]; St[id] = ts[idx];
}
__global__ void k_mk_fmaj(const float* tc, const float* ts, float* Cf, float* Sf){
    int id = blockIdx.x*256 + threadIdx.x;
    if (id >= SEQL*FRQ) return;
    int t = id % SEQL, f = id / SEQL;
    int idx = (f*t) % SEQL;
    Cf[id] = tc[idx]; Sf[id] = ts[idx];
}

// ---- softmax over w_c rows ----
__global__ void k_wcsm(const float* w_c, float* wcs){
    int w = blockIdx.x; int j = threadIdx.x;
    __shared__ float red[EMB];
    float v = w_c[w*EMB + j];
    red[j] = v; __syncthreads();
    for (int s = 64; s > 0; s >>= 1){ if (j < s) red[j] = fmaxf(red[j], red[j+s]); __syncthreads(); }
    float m = red[0]; __syncthreads();
    float e = expf(v - m);
    red[j] = e; __syncthreads();
    for (int s = 64; s > 0; s >>= 1){ if (j < s) red[j] += red[j+s]; __syncthreads(); }
    wcs[w*EMB + j] = e / red[0];
}

// ---- ew[w,j] = sum_i emb[i] * fgc_w[w,0,ri,i,j] ----
__global__ void k_ew(const float* emb, const float* fgc_w, float* ewr, float* ewi){
    int id = blockIdx.x*256 + threadIdx.x;
    if (id >= NWW*EMB) return;
    int w = id / EMB, j = id % EMB;
    const float* wr = fgc_w + ((size_t)(w*LAYN + 0)*2 + 0)*EMB*EMB;
    const float* wi = wr + (size_t)EMB*EMB;
    float ar = 0.f, ai = 0.f;
    for (int i = 0; i < EMB; i++){
        float e = emb[i];
        ar += e * wr[i*EMB + j];
        ai += e * wi[i*EMB + j];
    }
    ewr[id] = ar; ewi[id] = ai;
}

// ---- forward DFT of win_seq rows, 4 bw per block, split over t into 4 chunks ----
// writes RAW partial sums (scale + sign applied in k_fgc_fused layer 0)
#define DFT_TCH 290
__global__ void k_dft(const float* ws, const float* Ct, const float* St,
                      float* pre, float* pim){
    __shared__ float X[4][DFT_TCH];
    int f = blockIdx.x*256 + threadIdx.x;   // grid.x = 3
    int bw0 = blockIdx.y*4;                 // grid.y = 68
    int t0 = blockIdx.z*DFT_TCH;            // grid.z = 4
    for (int e = threadIdx.x; e < 4*DFT_TCH; e += 256){
        int g = e / DFT_TCH, t = e % DFT_TCH;
        X[g][t] = ws[(size_t)(bw0+g)*SEQL + t0 + t];
    }
    __syncthreads();
    if (f >= FRQ) return;
    float sr[4] = {0,0,0,0}, si[4] = {0,0,0,0};
    #pragma unroll 2
    for (int tt = 0; tt < DFT_TCH; tt++){
        int t = t0 + tt;
        float ct_ = Ct[(size_t)t*FRQ + f];
        float st_ = St[(size_t)t*FRQ + f];
        #pragma unroll
        for (int g = 0; g < 4; g++){
            sr[g] += X[g][tt]*ct_;
            si[g] += X[g][tt]*st_;
        }
    }
    size_t base = (size_t)blockIdx.z*NBW;
    #pragma unroll
    for (int g = 0; g < 4; g++){
        pre[(base + bw0+g)*FRQ + f] = sr[g];
        pim[(base + bw0+g)*FRQ + f] = si[g];
    }
}

// ---- weight prep: transpose + scale + fp16 hi/lo split, packed in MFMA fragment
// order so the GEMM kernel's loads are wave-contiguous (1 KB per instruction).
__global__ void k_wprep(const float* fgc_w, _Float16* Wpk){
    __shared__ float T[128][129];
    int blk = blockIdx.x;              // 0..135
    int ri = blk & 1; int wl = blk >> 1;    // wl = w*4 + lm1
    int w = wl >> 2; int lm1 = wl & 3;
    const float* src = fgc_w + ((size_t)(w*LAYN + lm1+1)*2 + ri)*EMB*EMB;
    for (int e = threadIdx.x; e < 16384; e += 256){
        int i = e >> 7, j = e & 127;
        T[i][j] = src[e] * SWF;
    }
    __syncthreads();
    size_t base = (size_t)wl*65536;
    _Float16* hi = Wpk + base + (size_t)(2*ri)*16384;
    _Float16* lo = Wpk + base + (size_t)(2*ri+1)*16384;
    for (int c8 = 0; c8 < 8; c8++){
        int d0 = c8*2048 + threadIdx.x*8;
        int nb = d0 >> 11; int rem = d0 & 2047;
        int kc = rem >> 9; int l = (rem & 511) >> 3;
        int q = l >> 4, cc = l & 15;
        int n = nb*16 + cc;
        half8 hv, lv;
        #pragma unroll
        for (int jj = 0; jj < 8; jj++){
            int k = kc*32 + q*8 + jj;
            float v = T[k][n];
            _Float16 h = (_Float16)v;
            hv[jj] = h; lv[jj] = (_Float16)(v - (float)h);
        }
        *(half8*)&hi[d0] = hv;
        *(half8*)&lo[d0] = lv;
    }
}

// ---- fused FGC: layer0 (rank-1, folds DFT partial combine) + 4 complex GEMM
// layers (f16 split MFMA) + zred.
// A-plane layout: row*128 halfs + XOR swizzle of 16B chunks -> conflict-free
// ds_read_b128 / ds_write_b128 (8 words/bank, the hardware minimum).
#define AIDX(row, jc) (((row)<<7) + ((((jc) ^ ((row)&15))) << 3))
#define OLD 132   // OUT row stride in floats (16B-aligned rows for float4 reads)
__launch_bounds__(256, 3)
__global__ void k_fgc_fused(const float* pre, const float* pim,
                            const float* ewr, const float* ewi,
                            const float* fgc_b, const float* wcs,
                            const _Float16* Wpk,
                            float* zre, float* zim){
    __shared__ __align__(16) _Float16 AhR[32*128];
    __shared__ __align__(16) _Float16 AlR[32*128];
    __shared__ __align__(16) _Float16 AhI[32*128];
    __shared__ __align__(16) _Float16 AlI[32*128];
    __shared__ __align__(16) float OUTR[16*OLD];
    __shared__ __align__(16) float OUTI[16*OLD];
    int tid = threadIdx.x;
    // w-major block order: resident window shares few Wpk chunks -> L2-resident W
    int by = blockIdx.y; int w = by >> 4; int b = by & 15;
    int bw = b*NWW + w;
    int f0 = blockIdx.x * 32;
    int lane = tid & 63, wv = tid >> 6;
    int c = lane & 15, q = lane >> 4;

    // ---- layer 0: X0[f][j] = relu(wre*ewr - wim*ewi + br - lam), split to LDS ----
    {
        int f = tid >> 3;            // 0..31
        int j0 = (tid & 7) << 4;     // 0..112
        int fg = f0 + f;
        float re = 0.f, im = 0.f;
        if (fg < FRQ){
            size_t o = (size_t)bw*FRQ + fg;
            const size_t PS = (size_t)NBW*FRQ;
            float r  = pre[o] + pre[PS+o] + pre[2*PS+o] + pre[3*PS+o];
            float i_ = pim[o] + pim[PS+o] + pim[2*PS+o] + pim[3*PS+o];
            const float sc = 0.02936128f; // 1/sqrt(1160)
            re = r * sc;
            im = -i_ * sc;
        }
        const float* br = fgc_b + (size_t)(w*LAYN + 0)*2*EMB;
        const float* bi = br + EMB;
        #pragma unroll
        for (int g = 0; g < 2; g++){
            half8 hR, lR, hI, lI;
            #pragma unroll
            for (int u = 0; u < 8; u++){
                int jj = j0 + g*8 + u;
                float er = ewr[w*EMB + jj], ei = ewi[w*EMB + jj];
                float xr = fmaxf(re*er - im*ei + br[jj] - LAMW, 0.f) * SXF;
                float xi = fmaxf(im*er + re*ei + bi[jj] - LAMW, 0.f) * SXF;
                _Float16 h1 = (_Float16)xr; hR[u] = h1; lR[u] = (_Float16)(xr - (float)h1);
                _Float16 h2 = (_Float16)xi; hI[u] = h2; lI[u] = (_Float16)(xi - (float)h2);
            }
            int jc = (tid & 7)*2 + g;
            int ao = AIDX(f, jc);
            *(half8*)&AhR[ao] = hR;
            *(half8*)&AlR[ao] = lR;
            *(half8*)&AhI[ao] = hI;
            *(half8*)&AlI[ao] = lI;
        }
    }
    __syncthreads();

    for (int l = 1; l <= 4; l++){
        const _Float16* Wb = Wpk + (size_t)(w*4 + (l-1))*65536;
        float4v Prr[2][2], Pii[2][2], Pri[2][2], Pir[2][2];
        #pragma unroll
        for (int rt = 0; rt < 2; rt++)
            #pragma unroll
            for (int ct = 0; ct < 2; ct++){
                #pragma unroll
                for (int u = 0; u < 4; u++){
                    Prr[rt][ct][u] = 0.f; Pii[rt][ct][u] = 0.f;
                    Pri[rt][ct][u] = 0.f; Pir[rt][ct][u] = 0.f;
                }
            }
        for (int kc = 0; kc < 4; kc++){
            half8 ahR[2], alR[2], ahI[2], alI[2];
            #pragma unroll
            for (int rt = 0; rt < 2; rt++){
                int ao = AIDX(rt*16 + c, kc*4 + q);
                ahR[rt] = *(const half8*)&AhR[ao];
                alR[rt] = *(const half8*)&AlR[ao];
                ahI[rt] = *(const half8*)&AhI[ao];
                alI[rt] = *(const half8*)&AlI[ao];
            }
            #pragma unroll
            for (int ct = 0; ct < 2; ct++){
                int off = ((wv*2 + ct)*2048) + kc*512 + lane*8;  // wave-contiguous
                half8 whR = *(const half8*)&Wb[off];
                half8 wlR = *(const half8*)&Wb[16384 + off];
                half8 whI = *(const half8*)&Wb[32768 + off];
                half8 wlI = *(const half8*)&Wb[49152 + off];
                #pragma unroll
                for (int rt = 0; rt < 2; rt++){
                    // Ar*Wr
                    Prr[rt][ct] = __builtin_amdgcn_mfma_f32_16x16x32_f16(ahR[rt], whR, Prr[rt][ct], 0,0,0);
                    Prr[rt][ct] = __builtin_amdgcn_mfma_f32_16x16x32_f16(ahR[rt], wlR, Prr[rt][ct], 0,0,0);
                    Prr[rt][ct] = __builtin_amdgcn_mfma_f32_16x16x32_f16(alR[rt], whR, Prr[rt][ct], 0,0,0);
                    // Ai*Wi
                    Pii[rt][ct] = __builtin_amdgcn_mfma_f32_16x16x32_f16(ahI[rt], whI, Pii[rt][ct], 0,0,0);
                    Pii[rt][ct] = __builtin_amdgcn_mfma_f32_16x16x32_f16(ahI[rt], wlI, Pii[rt][ct], 0,0,0);
                    Pii[rt][ct] = __builtin_amdgcn_mfma_f32_16x16x32_f16(alI[rt], whI, Pii[rt][ct], 0,0,0);
                    // Ar*Wi
                    Pri[rt][ct] = __builtin_amdgcn_mfma_f32_16x16x32_f16(ahR[rt], whI, Pri[rt][ct], 0,0,0);
                    Pri[rt][ct] = __builtin_amdgcn_mfma_f32_16x16x32_f16(ahR[rt], wlI, Pri[rt][ct], 0,0,0);
                    Pri[rt][ct] = __builtin_amdgcn_mfma_f32_16x16x32_f16(alR[rt], whI, Pri[rt][ct], 0,0,0);
                    // Ai*Wr
                    Pir[rt][ct] = __builtin_amdgcn_mfma_f32_16x16x32_f16(ahI[rt], whR, Pir[rt][ct], 0,0,0);
                    Pir[rt][ct] = __builtin_amdgcn_mfma_f32_16x16x32_f16(ahI[rt], wlR, Pir[rt][ct], 0,0,0);
                    Pir[rt][ct] = __builtin_amdgcn_mfma_f32_16x16x32_f16(alI[rt], whR, Pir[rt][ct], 0,0,0);
                }
            }
        }
        __syncthreads();   // all waves done reading A planes
        const float* bR = fgc_b + (size_t)(w*LAYN + l)*2*EMB;
        const float* bI = bR + EMB;
        #pragma unroll
        for (int chunk = 0; chunk < 2; chunk++){
            // epilogue: rows chunk*16..+16, this wave's 32 cols (D: col=lane&15, row=q*4+reg)
            #pragma unroll
            for (int ct = 0; ct < 2; ct++){
                int n = wv*32 + ct*16 + c;
                float biasR = bR[n] - LAMW, biasI = bI[n] - LAMW;
                #pragma unroll
                for (int r = 0; r < 4; r++){
                    int row = q*4 + r;
                    float vR = (Prr[chunk][ct][r] - Pii[chunk][ct][r])*INVS + biasR;
                    float vI = (Pir[chunk][ct][r] + Pri[chunk][ct][r])*INVS + biasI;
                    OUTR[row*OLD + n] = fmaxf(vR, 0.f);
                    OUTI[row*OLD + n] = fmaxf(vI, 0.f);
                }
            }
            __syncthreads();
            if (l < 4){
                // repack chunk into A planes (split to fp16 hi/lo, scaled)
                int fch = tid >> 4;            // 0..15
                int j0r = (tid & 15) << 3;     // 0..120
                float4v ra = *(const float4v*)&OUTR[fch*OLD + j0r];
                float4v rb = *(const float4v*)&OUTR[fch*OLD + j0r + 4];
                float4v ia = *(const float4v*)&OUTI[fch*OLD + j0r];
                float4v ib = *(const float4v*)&OUTI[fch*OLD + j0r + 4];
                half8 hR, lR, hI, lI;
                #pragma unroll
                for (int u = 0; u < 4; u++){
                    float xr = ra[u] * SXF;
                    float xi = ia[u] * SXF;
                    _Float16 h1 = (_Float16)xr; hR[u] = h1; lR[u] = (_Float16)(xr - (float)h1);
                    _Float16 h2 = (_Float16)xi; hI[u] = h2; lI[u] = (_Float16)(xi - (float)h2);
                }
                #pragma unroll
                for (int u = 0; u < 4; u++){
                    float xr = rb[u] * SXF;
                    float xi = ib[u] * SXF;
                    _Float16 h1 = (_Float16)xr; hR[4+u] = h1; lR[4+u] = (_Float16)(xr - (float)h1);
                    _Float16 h2 = (_Float16)xi; hI[4+u] = h2; lI[4+u] = (_Float16)(xi - (float)h2);
                }
                int ao = AIDX(chunk*16 + fch, (tid & 15));
                *(half8*)&AhR[ao] = hR;
                *(half8*)&AlR[ao] = lR;
                *(half8*)&AhI[ao] = hI;
                *(half8*)&AlI[ao] = lI;
            } else {
                // final layer: contract with softmaxed w_c over EMB -> zre/zim
                int fch = tid >> 4;
                int j0r = (tid & 15) << 3;
                float4v ra = *(const float4v*)&OUTR[fch*OLD + j0r];
                float4v rb = *(const float4v*)&OUTR[fch*OLD + j0r + 4];
                float4v ia = *(const float4v*)&OUTI[fch*OLD + j0r];
                float4v ib = *(const float4v*)&OUTI[fch*OLD + j0r + 4];
                float sR = 0.f, sI = 0.f;
                #pragma unroll
                for (int u = 0; u < 4; u++){
                    float cwa = wcs[w*EMB + j0r + u];
                    float cwb = wcs[w*EMB + j0r + 4 + u];
                    sR += ra[u]*cwa + rb[u]*cwb;
                    sI += ia[u]*cwa + ib[u]*cwb;
                }
                #pragma unroll
                for (int o = 8; o > 0; o >>= 1){
                    sR += __shfl_down(sR, o, 64);
                    sI += __shfl_down(sI, o, 64);
                }
                int fg = f0 + chunk*16 + fch;
                if ((tid & 15) == 0 && fg < FRQ){
                    zre[(size_t)bw*FRQ + fg] = sR;
                    zim[(size_t)bw*FRQ + fg] = sI;
                }
            }
            __syncthreads();
        }
    }
}

// ---- inverse DFT, 4 bw per block, split over f into 4 chunks; small combine ----
#define IR_FCH 145
__global__ void k_irfft(const float* zre, const float* zim, const float* Cf, const float* Sf,
                        float* part){
    __shared__ float ZR[4][IR_FCH+1];
    __shared__ float ZI[4][IR_FCH+1];
    int t = blockIdx.x*256 + threadIdx.x;   // grid.x = 5
    int bw0 = blockIdx.y*4;                 // grid.y = 68
    int f0 = 1 + blockIdx.z*IR_FCH;         // grid.z = 4 -> covers f=1..579
    int fn = min(f0 + IR_FCH, FRQ-1) - f0;  // 145 or 144
    for (int e = threadIdx.x; e < 4*fn; e += 256){
        int g = e / fn, f = e % fn;
        ZR[g][f] = zre[(size_t)(bw0+g)*FRQ + f0 + f];
        ZI[g][f] = zim[(size_t)(bw0+g)*FRQ + f0 + f];
    }
    __syncthreads();
    if (t >= SEQL) return;
    float acc[4] = {0,0,0,0};
    #pragma unroll 2
    for (int ff_ = 0; ff_ < fn; ff_++){
        int f = f0 + ff_;
        float cf = Cf[(size_t)f*SEQL + t];
        float sf = Sf[(size_t)f*SEQL + t];
        #pragma unroll
        for (int g = 0; g < 4; g++)
            acc[g] += ZR[g][ff_]*cf - ZI[g][ff_]*sf;
    }
    size_t base = (size_t)blockIdx.z*NBW;
    #pragma unroll
    for (int g = 0; g < 4; g++)
        part[(base + bw0+g)*SEQL + t] = acc[g];
}
__global__ void k_irfftc(const float* part, const float* zre, float* ff){
    int id = blockIdx.x*256 + threadIdx.x;
    if (id >= NBW*SEQL) return;
    int t = id % SEQL; int bw = id / SEQL;
    const size_t NS = (size_t)NBW*SEQL;
    float s = part[id] + part[NS + id] + part[2*NS + id] + part[3*NS + id];
    float sgn = (t & 1) ? -1.f : 1.f;
    float v = zre[(size_t)bw*FRQ] + 2.f*s + sgn*zre[(size_t)bw*FRQ + FRQ-1];
    ff[id] = v * 0.02936128f; // 1/sqrt(1160)
}

// ---- x1 = mean over NW of win_pcc ----
__global__ void k_x1mean(const float* pcc, float* x1){
    int id = blockIdx.x*256 + threadIdx.x;
    if (id >= BSZ*NRR*NRR) return;
    const float* p = pcc + (size_t)id*NWW;
    float s = 0.f;
    for (int w = 0; w < NWW; w++) s += p[w];
    x1[id] = s * (1.f/NWW);
}

__global__ void k_dt1(const float* x1, const float* Wdt1, float* dt1){
    int id = blockIdx.x*256 + threadIdx.x;
    if (id >= BSZ*NRR*NRR) return;
    int c = id % NRR; int bt = id / NRR;
    const float* xr = x1 + (size_t)bt*NRR;
    float s = 0.f;
    for (int m = 0; m < NRR; m++) s += xr[m] * Wdt1[m*NRR + c];
    dt1[id] = softplus_f(s);
}
__global__ void k_btct1(const float* x1, const float* WB1, const float* WC1,
                        float* BT1, float* CT1){
    int id = blockIdx.x*256 + threadIdx.x;
    if (id >= BSZ*NRR*DST) return;
    int s_ = id % DST; int bt = id / DST;
    const float* xr = x1 + (size_t)bt*NRR;
    float sb = 0.f, sc = 0.f;
    for (int m = 0; m < NRR; m++){ float v = xr[m]; sb += v*WB1[m*DST + s_]; sc += v*WC1[m*DST + s_]; }
    BT1[id] = sb; CT1[id] = sc;
}
// ---- sscan1: one lane per (b,c,s) state channel; cross-lane reduce at end only.
// pooled[b,c] = (D[c]*sum_t x + sum_s sum_t h[t,s]*Ct[t,s]) / NRR  -- no per-t sync needed.
__global__ void k_sscan1(const float* x1, const float* dt1, const float* BT1, const float* CT1,
                         const float* A1, const float* D1, float* pooled){
    int id = blockIdx.x*256 + threadIdx.x;
    if (id >= BSZ*NRR*DST) return;
    int s = id & 15; int bc = id >> 4;
    int c = bc % NRR, b = bc / NRR;
    float a = A1[c*DST + s];
    float h = 0.f, csum = 0.f, xsum = 0.f;
    for (int t = 0; t < NRR; t++){
        size_t o = (size_t)(b*NRR + t)*NRR + c;
        float dtv = dt1[o], xv = x1[o];
        size_t ro = (size_t)(b*NRR + t)*DST + s;
        h = expf(dtv*a)*h + dtv*xv*BT1[ro];
        csum += h*CT1[ro];
        xsum += xv;
    }
    #pragma unroll
    for (int o = 8; o > 0; o >>= 1) csum += __shfl_xor(csum, o, 16);
    if (s == 0) pooled[bc] = (csum + D1[c]*xsum) * (1.f/NRR);
}
__global__ void k_out1(const float* pooled, const float* Wout1, float* out1){
    int id = blockIdx.x*256 + threadIdx.x;
    if (id >= NBW*SEQL) return;
    int k = id % SEQL; int bw = id / SEQL; int w = bw % NWW; int b = bw / NWW;
    float s = 0.f;
    for (int d = 0; d < NRR; d++) s += pooled[b*NRR + d] * Wout1[((size_t)w*NRR + d)*SEQL + k];
    out1[id] = s;
}

// ---- layernorm over SEQ per (b,w) row ----
__global__ void k_ln(const float* in, const float* g, const float* bta, float* out){
    __shared__ float row[SEQL];
    __shared__ float red[256];
    int r = blockIdx.x; int tid = threadIdx.x;
    const float* x = in + (size_t)r*SEQL;
    float s = 0.f;
    for (int i = tid; i < SEQL; i += 256){ float v = x[i]; row[i] = v; s += v; }
    red[tid] = s; __syncthreads();
    for (int st = 128; st > 0; st >>= 1){ if (tid < st) red[tid] += red[tid+st]; __syncthreads(); }
    float m = red[0] * (1.f/SEQL); __syncthreads();
    float vs = 0.f;
    for (int i = tid; i < SEQL; i += 256){ float d = row[i] - m; vs += d*d; }
    red[tid] = vs; __syncthreads();
    for (int st = 128; st > 0; st >>= 1){ if (tid < st) red[tid] += red[tid+st]; __syncthreads(); }
    float inv = 1.f / sqrtf(red[0]*(1.f/SEQL) + EPSW);
    for (int i = tid; i < SEQL; i += 256)
        out[(size_t)r*SEQL + i] = (row[i] - m)*inv*g[i] + bta[i];
}
// ---- layernorm that sums 4 split-K partials on load (combine folded in) ----
__global__ void k_ln4(const float* part, const float* g, const float* bta, float* out){
    __shared__ float row[SEQL];
    __shared__ float red[256];
    int r = blockIdx.x; int tid = threadIdx.x;
    const size_t NS = (size_t)NBW*SEQL;
    const float* x = part + (size_t)r*SEQL;
    float s = 0.f;
    for (int i = tid; i < SEQL; i += 256){
        float v = x[i] + x[NS + i] + x[2*NS + i] + x[3*NS + i];
        row[i] = v; s += v;
    }
    red[tid] = s; __syncthreads();
    for (int st = 128; st > 0; st >>= 1){ if (tid < st) red[tid] += red[tid+st]; __syncthreads(); }
    float m = red[0] * (1.f/SEQL); __syncthreads();
    float vs = 0.f;
    for (int i = tid; i < SEQL; i += 256){ float d = row[i] - m; vs += d*d; }
    red[tid] = vs; __syncthreads();
    for (int st = 128; st > 0; st >>= 1){ if (tid < st) red[tid] += red[tid+st]; __syncthreads(); }
    float inv = 1.f / sqrtf(red[0]*(1.f/SEQL) + EPSW);
    for (int i = tid; i < SEQL; i += 256)
        out[(size_t)r*SEQL + i] = (row[i] - m)*inv*g[i] + bta[i];
}

__global__ void k_x2(const float* ga, const float* ff, float* x2){
    int id = blockIdx.x*256 + threadIdx.x;
    if (id >= NBW*SEQL) return;
    int within = id % SEQL; int q = within % WSS; int n = within / WSS;
    int bw = id / SEQL; int w = bw % NWW; int b = bw / NWW;
    const float* gr = ga + ((size_t)b*NRR + n)*NRR;
    const float* fr = ff + (size_t)(b*NWW + w)*SEQL + q;
    float s = 0.f;
    for (int m = 0; m < NRR; m++) s += gr[m] * fr[m*WSS];
    x2[id] = s;
}
// ---- dt2: 4 rows per block, split over m into 4 chunks; RAW partials
// (softplus + combine folded into k_sscan2) ----
#define DT_MCH 290
__global__ void k_dt2(const float* x2, const float* Wdt2, float* part){
    __shared__ float X[4][DT_MCH];
    int c = blockIdx.x*256 + threadIdx.x;   // grid.x = 5
    int bt0 = blockIdx.y*4;                 // grid.y = 68
    int m0 = blockIdx.z*DT_MCH;             // grid.z = 4
    for (int e = threadIdx.x; e < 4*DT_MCH; e += 256){
        int g = e / DT_MCH, m = e % DT_MCH;
        X[g][m] = x2[(size_t)(bt0+g)*SEQL + m0 + m];
    }
    __syncthreads();
    if (c >= SEQL) return;
    float a[4] = {0,0,0,0};
    #pragma unroll 2
    for (int mm = 0; mm < DT_MCH; mm++){
        float wv_ = Wdt2[(size_t)(m0+mm)*SEQL + c];
        #pragma unroll
        for (int g = 0; g < 4; g++) a[g] += X[g][mm]*wv_;
    }
    size_t base = (size_t)blockIdx.z*NBW;
    #pragma unroll
    for (int g = 0; g < 4; g++)
        part[(base + bt0+g)*SEQL + c] = a[g];
}
// ---- btct2: one block per bt row, threads split (s, m-chunk), LDS tree reduce ----
__global__ void k_btct2(const float* x2, const float* WB2, const float* WC2,
                        float* BT2, float* CT2){
    __shared__ float SB[256], SC[256];
    int bt = blockIdx.x;            // 0..271
    int tid = threadIdx.x;
    int s = tid & 15, mc = tid >> 4;   // 16 chunks of <=73
    int m0 = mc*73, m1 = min(m0 + 73, SEQL);
    const float* xr = x2 + (size_t)bt*SEQL;
    float sb = 0.f, sc = 0.f;
    for (int m = m0; m < m1; m++){
        float v = xr[m];
        sb += v*WB2[m*DST + s];
        sc += v*WC2[m*DST + s];
    }
    SB[tid] = sb; SC[tid] = sc; __syncthreads();
    for (int st = 128; st >= 16; st >>= 1){
        if (tid < st){ SB[tid] += SB[tid+st]; SC[tid] += SC[tid+st]; }
        __syncthreads();
    }
    if (tid < 16){
        BT2[bt*DST + tid] = SB[tid];
        CT2[bt*DST + tid] = SC[tid];
    }
}
__global__ void k_sscan2(const float* x2, const float* dtp, const float* BT2, const float* CT2,
                         const float* A2, const float* D2, float* y2){
    int id = blockIdx.x*256 + threadIdx.x;
    if (id >= BSZ*SEQL) return;
    int c = id % SEQL, b = id / SEQL;
    const size_t NS = (size_t)NBW*SEQL;
    float a[DST], h[DST];
    #pragma unroll
    for (int s = 0; s < DST; s++){ a[s] = A2[c*DST + s]; h[s] = 0.f; }
    float dv = D2[c];
    for (int t = 0; t < NWW; t++){
        size_t o = (size_t)(b*NWW + t)*SEQL + c;
        float dtv = softplus_f(dtp[o] + dtp[NS+o] + dtp[2*NS+o] + dtp[3*NS+o]);
        float xv = x2[o];
        float dx = dtv * xv;
        const float* bt = BT2 + (size_t)(b*NWW + t)*DST;
        const float* ct = CT2 + (size_t)(b*NWW + t)*DST;
        float y = dv * xv;
        #pragma unroll
        for (int s = 0; s < DST; s++){
            h[s] = expf(dtv*a[s])*h[s] + dx*bt[s];
            y += h[s]*ct[s];
        }
        y2[o] = y;
    }
}
// ---- out2: 4 rows per block, split over m into 4 chunks; combine folded into k_ln4 ----
__global__ void k_out2(const float* y2, const float* Wout2, float* part){
    __shared__ float Y[4][DT_MCH];
    int k = blockIdx.x*256 + threadIdx.x;   // grid.x = 5
    int bw0 = blockIdx.y*4;                 // grid.y = 68
    int m0 = blockIdx.z*DT_MCH;             // grid.z = 4
    for (int e = threadIdx.x; e < 4*DT_MCH; e += 256){
        int g = e / DT_MCH, m = e % DT_MCH;
        Y[g][m] = y2[(size_t)(bw0+g)*SEQL + m0 + m];
    }
    __syncthreads();
    if (k >= SEQL) return;
    float a[4] = {0,0,0,0};
    #pragma unroll 2
    for (int mm = 0; mm < DT_MCH; mm++){
        float wv_ = Wout2[(size_t)(m0+mm)*SEQL + k];
        #pragma unroll
        for (int g = 0; g < 4; g++) a[g] += Y[g][mm]*wv_;
    }
    size_t base = (size_t)blockIdx.z*NBW;
    #pragma unroll
    for (int g = 0; g < 4; g++)
        part[(base + bw0+g)*SEQL + k] = a[g];
}

// ---- gate + fusion ----
__global__ void k_gatefusion(const float* fr2, const float* tf, const float* W_gate,
                             const float* b_gate, float* fusion){
    int id = blockIdx.x*256 + threadIdx.x;
    if (id >= BSZ*NRR*EDD) return;
    int j = id % EDD; int n = (id / EDD) % NRR; int b = id / (EDD*NRR);
    float acc = b_gate[j];
    for (int w = 0; w < NWW; w++){
        const float* f2 = fr2 + (size_t)(b*NWW + w)*SEQL + n*WSS;
        const float* tp = tf  + (size_t)(b*NWW + w)*SEQL + n*WSS;
        const float* wg = W_gate + (size_t)(w*2*WSS)*EDD + j;
        #pragma unroll
        for (int q = 0; q < WSS; q++) acc += f2[q]*wg[q*EDD];
        #pragma unroll
        for (int q = 0; q < WSS; q++) acc += tp[q]*wg[(WSS+q)*EDD];
    }
    float gt = sigmoid_f(acc);
    int w_ = j / WSS, q_ = j % WSS;
    float fp = fr2[(size_t)(b*NWW + w_)*SEQL + n*WSS + q_];
    float tp = tf [(size_t)(b*NWW + w_)*SEQL + n*WSS + q_];
    fusion[id] = gt*fp + (1.f - gt)*tp;
}

// ---- router: LN(170) -> 4 logits -> top2 softmax gates ----
__global__ void k_gates(const float* fusion, const float* rg, const float* rb,
                        const float* Wr, const float* brr, float* gatesE){
    int bn = blockIdx.x; int lane = threadIdx.x;
    const float* x = fusion + (size_t)bn*EDD;
    bool v2ok = (lane + 128) < EDD;
    float v0 = x[lane];
    float v1 = x[lane + 64];
    float v2 = v2ok ? x[lane + 128] : 0.f;
    float s = v0 + v1 + v2;
    for (int o = 32; o > 0; o >>= 1) s += __shfl_xor(s, o, 64);
    float m = s * (1.f/EDD);
    float d0 = v0 - m, d1 = v1 - m, d2 = v2ok ? (v2 - m) : 0.f;
    float vs = d0*d0 + d1*d1 + d2*d2;
    for (int o = 32; o > 0; o >>= 1) vs += __shfl_xor(vs, o, 64);
    float inv = 1.f / sqrtf(vs*(1.f/EDD) + EPSW);
    float r0 = d0*inv*rg[lane] + rb[lane];
    float r1 = d1*inv*rg[lane+64] + rb[lane+64];
    float r2 = v2ok ? (d2*inv*rg[lane+128] + rb[lane+128]) : 0.f;
    float pl[4];
    #pragma unroll
    for (int e = 0; e < 4; e++){
        float p = r0*Wr[lane*4 + e] + r1*Wr[(lane+64)*4 + e];
        if (v2ok) p += r2*Wr[(lane+128)*4 + e];
        for (int o = 32; o > 0; o >>= 1) p += __shfl_xor(p, o, 64);
        pl[e] = p;
    }
    if (lane == 0){
        float lg[4];
        #pragma unroll
        for (int e = 0; e < 4; e++) lg[e] = pl[e] + brr[e];
        int i0 = 0;
        for (int e = 1; e < 4; e++) if (lg[e] > lg[i0]) i0 = e;
        int i1 = -1;
        for (int e = 0; e < 4; e++) if (e != i0 && (i1 < 0 || lg[e] > lg[i1])) i1 = e;
        float e1 = expf(lg[i1] - lg[i0]);
        float w0 = 1.f/(1.f + e1), w1 = e1/(1.f + e1);
        float g[4] = {0.f,0.f,0.f,0.f};
        g[i0] = w0; g[i1] = w1;
        #pragma unroll
        for (int e = 0; e < 4; e++) gatesE[bn*4 + e] = g[e];
    }
}

__global__ void k_support(const float* fusion, const float* We, float* support){
    int id = blockIdx.x*256 + threadIdx.x;
    if (id >= BSZ*4*NRR*EDD) return;
    int g = id % EDD; int n = (id / EDD) % NRR; int e = (id / (EDD*NRR)) % 4; int b = id / (EDD*NRR*4);
    const float* fu = fusion + ((size_t)b*NRR + n)*EDD;
    const float* w = We + (size_t)e*EDD*EDD + g;
    float s = 0.f;
    for (int f = 0; f < EDD; f++) s += fu[f] * w[(size_t)f*EDD];
    support[id] = s;
}
__global__ void k_eout(const float* ga, const float* support, float* eout){
    int id = blockIdx.x*256 + threadIdx.x;
    if (id >= BSZ*4*NRR*EDD) return;
    int g = id % EDD; int n = (id / EDD) % NRR; int e = (id / (EDD*NRR)) % 4; int b = id / (EDD*NRR*4);
    const float* gr = ga + ((size_t)b*NRR + n)*NRR;
    const float* sp = support + ((size_t)(b*4 + e)*NRR)*EDD + g;
    float s = 0.f;
    for (int m = 0; m < NRR; m++) s += gr[m] * sp[(size_t)m*EDD];
    eout[id] = fmaxf(s, 0.f);
}
__global__ void k_moe(const float* eout, const float* gatesE, float* moe){
    int id = blockIdx.x*256 + threadIdx.x;
    if (id >= BSZ*NRR*EDD) return;
    int g = id % EDD; int n = (id / EDD) % NRR; int b = id / (EDD*NRR);
    const float* gt = gatesE + ((size_t)b*NRR + n)*4;
    float s = 0.f;
    #pragma unroll
    for (int e = 0; e < 4; e++)
        s += eout[((size_t)(b*4 + e)*NRR + n)*EDD + g] * gt[e];
    moe[id] = s;
}

#define MLPK (NRR*EDD)   // 19720
#define KSPLIT 80
#define KCH 247
// mlp1: all 16 batch rows share one read of the W1 chunk; moe chunk staged in LDS
__global__ void k_mlp1p(const float* moe, const float* W1, float* part1){
    __shared__ float M[16*KCH];   // 15.8 KB
    int kc = blockIdx.x;          // 0..79
    int j = blockIdx.y*256 + threadIdx.x;  // grid.y = 2
    int i0 = kc*KCH; int len = MLPK - i0; if (len > KCH) len = KCH;
    for (int e = threadIdx.x; e < 16*len; e += 256){
        int b = e / len, i = e % len;
        M[b*KCH + i] = moe[(size_t)b*MLPK + i0 + i];
    }
    __syncthreads();
    float acc[16];
    #pragma unroll
    for (int b = 0; b < 16; b++) acc[b] = 0.f;
    for (int i = 0; i < len; i++){
        float wv_ = W1[(size_t)(i0+i)*512 + j];
        #pragma unroll
        for (int b = 0; b < 16; b++) acc[b] += M[b*KCH + i]*wv_;
    }
    #pragma unroll
    for (int b = 0; b < 16; b++)
        part1[((size_t)kc*BSZ + b)*512 + j] = acc[b];
}
__global__ void k_mlp1c(const float* part1, const float* b1, float* h1){
    int id = blockIdx.x*256 + threadIdx.x;
    if (id >= BSZ*512) return;
    float s = 0.f;
    for (int kc = 0; kc < KSPLIT; kc++) s += part1[(size_t)kc*BSZ*512 + id];
    const float sc = 0.99999500003750f; // 1/sqrt(1+1e-5)
    h1[id] = fmaxf((s + b1[id % 512]) * sc, 0.f);
}
__global__ void k_mlp2(const float* h1, const float* W2, const float* b2, float* h2){
    int id = blockIdx.x*256 + threadIdx.x;
    if (id >= BSZ*256) return;
    int j = id % 256; int b = id / 256;
    const float* h = h1 + (size_t)b*512;
    float s = 0.f;
    for (int i = 0; i < 512; i++) s += h[i] * W2[(size_t)i*256 + j];
    const float sc = 0.99999500003750f;
    h2[id] = fmaxf((s + b2[j]) * sc, 0.f);
}
__global__ void k_mlp3(const float* h2, const float* W3, const float* b3, float* h3){
    int id = blockIdx.x*256 + threadIdx.x;
    if (id >= BSZ*128) return;
    int j = id % 128; int b = id / 128;
    const float* h = h2 + (size_t)b*256;
    float s = 0.f;
    for (int i = 0; i < 256; i++) s += h[i] * W3[(size_t)i*128 + j];
    const float sc = 0.99999500003750f;
    h3[id] = fmaxf((s + b3[j]) * sc, 0.f);
}
__global__ void k_mlp4(const float* h3, const float* W4, const float* b4, float* out){
    int id = threadIdx.x;
    if (id >= BSZ*2) return;
    int o = id % 2; int b = id / 2;
    const float* h = h3 + (size_t)b*128;
    float s = 0.f;
    for (int i = 0; i < 128; i++) s += h[i] * W4[i*2 + o];
    out[id] = s + b4[o];
}

extern "C" void kernel_launch(void* const* d_in, const int* in_sizes, int n_in,
                              void* d_out, int out_size, void* d_ws, size_t ws_size,
                              hipStream_t stream){
    (void)in_sizes; (void)n_in; (void)out_size;
    const float* win_seq = (const float*)d_in[0];
    const float* win_pcc = (const float*)d_in[1];
    const float* ga      = (const float*)d_in[2];
    const float* emb     = (const float*)d_in[4];
    const float* fgc_w   = (const float*)d_in[5];
    const float* fgc_b   = (const float*)d_in[6];
    const float* w_c     = (const float*)d_in[7];
    const float* ln_g    = (const float*)d_in[8];
    const float* ln_b    = (const float*)d_in[9];
    const float* A1      = (const float*)d_in[10];
    const float* WB1     = (const float*)d_in[11];
    const float* WC1     = (const float*)d_in[12];
    const float* Wdt1    = (const float*)d_in[13];
    const float* D1      = (const float*)d_in[14];
    const float* Wout1   = (const float*)d_in[15];
    const float* A2      = (const float*)d_in[16];
    const float* WB2     = (const float*)d_in[17];
    const float* WC2     = (const float*)d_in[18];
    const float* Wdt2    = (const float*)d_in[19];
    const float* D2      = (const float*)d_in[20];
    const float* Wout2   = (const float*)d_in[21];
    const float* W_gate  = (const float*)d_in[22];
    const float* b_gate  = (const float*)d_in[23];
    const float* rln_g   = (const float*)d_in[24];
    const float* rln_b   = (const float*)d_in[25];
    const float* Wr      = (const float*)d_in[26];
    const float* brr     = (const float*)d_in[27];
    const float* We      = (const float*)d_in[28];
    const float* W1      = (const float*)d_in[29];
    const float* b1      = (const float*)d_in[30];
    const float* W2      = (const float*)d_in[31];
    const float* b2      = (const float*)d_in[32];
    const float* W3      = (const float*)d_in[33];
    const float* b3      = (const float*)d_in[34];
    const float* W4      = (const float*)d_in[35];
    const float* b4      = (const float*)d_in[36];
    float* out = (float*)d_out;
    float* ws  = (float*)d_ws;

    size_t off = 0;
    auto alloc = [&](size_t n){ size_t o = off; off += (n + 63) & ~(size_t)63; return o; };
    size_t o_tabc = alloc(SEQL), o_tabs = alloc(SEQL);
    size_t o_Ct = alloc((size_t)SEQL*FRQ), o_St = alloc((size_t)SEQL*FRQ);
    size_t o_Cf = alloc((size_t)SEQL*FRQ), o_Sf = alloc((size_t)SEQL*FRQ);
    size_t o_wcs = alloc(NWW*EMB);
    size_t o_ewr = alloc(NWW*EMB), o_ewi = alloc(NWW*EMB);
    size_t o_wpk = alloc((size_t)2228224);    // 4,456,448 fp16 = 17*4*4*16384
    size_t o_zre = alloc((size_t)NBW*FRQ), o_zim = alloc((size_t)NBW*FRQ);
    size_t o_ff  = alloc((size_t)NBW*SEQL);
    size_t o_pa  = alloc((size_t)4*NBW*SEQL);  // split-K partials (irfft/dt2/out2; dft re)
    size_t o_pb  = alloc((size_t)4*NBW*FRQ);   // dft im partials
    size_t o_x1  = alloc((size_t)BSZ*NRR*NRR);
    size_t o_dt1 = alloc((size_t)BSZ*NRR*NRR);
    size_t o_BT1 = alloc((size_t)BSZ*NRR*DST), o_CT1 = alloc((size_t)BSZ*NRR*DST);
    size_t o_pool= alloc((size_t)BSZ*NRR);
    size_t o_o1  = alloc((size_t)NBW*SEQL);
    size_t o_tf  = alloc((size_t)NBW*SEQL);
    size_t o_x2  = alloc((size_t)NBW*SEQL);
    size_t o_BT2 = alloc((size_t)NBW*DST), o_CT2 = alloc((size_t)NBW*DST);
    size_t o_y2  = alloc((size_t)NBW*SEQL);
    size_t o_fr2 = alloc((size_t)NBW*SEQL);
    size_t o_fus = alloc((size_t)BSZ*NRR*EDD);
    size_t o_gte = alloc((size_t)BSZ*NRR*4);
    size_t o_sup = alloc((size_t)BSZ*4*NRR*EDD);
    size_t o_eo  = alloc((size_t)BSZ*4*NRR*EDD);
    size_t o_moe = alloc((size_t)BSZ*NRR*EDD);
    size_t o_p1  = alloc((size_t)KSPLIT*BSZ*512);
    size_t o_h1  = alloc((size_t)BSZ*512);
    size_t o_h2  = alloc((size_t)BSZ*256);
    size_t o_h3  = alloc((size_t)BSZ*128);
    if (ws_size < off*sizeof(float)) return; // workspace too small -> visible failure

    #define WSP(o) (ws + (o))
    int nMk = (SEQL*FRQ + 255)/256;
    k_tables<<<(SEQL+255)/256, 256, 0, stream>>>(WSP(o_tabc), WSP(o_tabs));
    k_mk_tmaj<<<nMk, 256, 0, stream>>>(WSP(o_tabc), WSP(o_tabs), WSP(o_Ct), WSP(o_St));
    k_mk_fmaj<<<nMk, 256, 0, stream>>>(WSP(o_tabc), WSP(o_tabs), WSP(o_Cf), WSP(o_Sf));
    k_wcsm<<<NWW, EMB, 0, stream>>>(w_c, WSP(o_wcs));
    k_ew<<<(NWW*EMB+255)/256, 256, 0, stream>>>(emb, fgc_w, WSP(o_ewr), WSP(o_ewi));
    k_wprep<<<136, 256, 0, stream>>>(fgc_w, (_Float16*)WSP(o_wpk));
    k_dft<<<dim3(3, 68, 4), 256, 0, stream>>>(win_seq, WSP(o_Ct), WSP(o_St), WSP(o_pa), WSP(o_pb));
    k_fgc_fused<<<dim3(19, NBW), 256, 0, stream>>>(WSP(o_pa), WSP(o_pb), WSP(o_ewr), WSP(o_ewi),
                                                   fgc_b, WSP(o_wcs),
                                                   (const _Float16*)WSP(o_wpk),
                                                   WSP(o_zre), WSP(o_zim));
    k_irfft<<<dim3(5, 68, 4), 256, 0, stream>>>(WSP(o_zre), WSP(o_zim), WSP(o_Cf), WSP(o_Sf), WSP(o_pa));
    k_irfftc<<<(NBW*SEQL+255)/256, 256, 0, stream>>>(WSP(o_pa), WSP(o_zre), WSP(o_ff));
    // branch 1: pcc -> sscan1 -> out1 -> LN
    k_x1mean<<<(BSZ*NRR*NRR+255)/256, 256, 0, stream>>>(win_pcc, WSP(o_x1));
    k_dt1<<<(BSZ*NRR*NRR+255)/256, 256, 0, stream>>>(WSP(o_x1), Wdt1, WSP(o_dt1));
    k_btct1<<<(BSZ*NRR*DST+255)/256, 256, 0, stream>>>(WSP(o_x1), WB1, WC1, WSP(o_BT1), WSP(o_CT1));
    k_sscan1<<<(BSZ*NRR*DST+255)/256, 256, 0, stream>>>(WSP(o_x1), WSP(o_dt1), WSP(o_BT1), WSP(o_CT1),
                                                        A1, D1, WSP(o_pool));
    k_out1<<<(NBW*SEQL+255)/256, 256, 0, stream>>>(WSP(o_pool), Wout1, WSP(o_o1));
    k_ln<<<NBW, 256, 0, stream>>>(WSP(o_o1), ln_g, ln_b, WSP(o_tf));
    // branch 2: freq_feat -> adj -> sscan2 -> out2 -> LN
    k_x2<<<(NBW*SEQL+255)/256, 256, 0, stream>>>(ga, WSP(o_ff), WSP(o_x2));
    k_dt2<<<dim3(5, 68, 4), 256, 0, stream>>>(WSP(o_x2), Wdt2, WSP(o_pa));
    k_btct2<<<NBW, 256, 0, stream>>>(WSP(o_x2), WB2, WC2, WSP(o_BT2), WSP(o_CT2));
    k_sscan2<<<(BSZ*SEQL+255)/256, 256, 0, stream>>>(WSP(o_x2), WSP(o_pa), WSP(o_BT2), WSP(o_CT2),
                                                     A2, D2, WSP(o_y2));
    k_out2<<<dim3(5, 68, 4), 256, 0, stream>>>(WSP(o_y2), Wout2, WSP(o_pa));
    k_ln4<<<NBW, 256, 0, stream>>>(WSP(o_pa), ln_g, ln_b, WSP(o_fr2));
    // fusion + MoE + MLP
    k_gatefusion<<<(BSZ*NRR*EDD+255)/256, 256, 0, stream>>>(WSP(o_fr2), WSP(o_tf), W_gate, b_gate, WSP(o_fus));
    k_gates<<<BSZ*NRR, 64, 0, stream>>>(WSP(o_fus), rln_g, rln_b, Wr, brr, WSP(o_gte));
    k_support<<<(BSZ*4*NRR*EDD+255)/256, 256, 0, stream>>>(WSP(o_fus), We, WSP(o_sup));
    k_eout<<<(BSZ*4*NRR*EDD+255)/256, 256, 0, stream>>>(ga, WSP(o_sup), WSP(o_eo));
    k_moe<<<(BSZ*NRR*EDD+255)/256, 256, 0, stream>>>(WSP(o_eo), WSP(o_gte), WSP(o_moe));
    k_mlp1p<<<dim3(KSPLIT, 2), 256, 0, stream>>>(WSP(o_moe), W1, WSP(o_p1));
    k_mlp1c<<<(BSZ*512)/256, 256, 0, stream>>>(WSP(o_p1), b1, WSP(o_h1));
    k_mlp2<<<(BSZ*256)/256, 256, 0, stream>>>(WSP(o_h1), W2, b2, WSP(o_h2));
    k_mlp3<<<(BSZ*128+255)/256, 256, 0, stream>>>(WSP(o_h2), W3, b3, WSP(o_h3));
    k_mlp4<<<1, 64, 0, stream>>>(WSP(o_h3), W4, b4, out);
    #undef WSP
}